// Round 13
// baseline (191.418 us; speedup 1.0000x reference)
//
#include <hip/hip_runtime.h>
#include <hip/hip_fp16.h>

// ---------------------------------------------------------------------------
// RoutingGNN: 2-layer GCN (sym-norm, self-loops) + linear head.
// Round 13: layer-2 gather was L2-capacity-bound (g16 6.4MB > 4MiB/XCD L2,
// 67MB L2-miss traffic). Feature-quarter split with XCD clustering:
// quarter = blockIdx%4 -> with round-robin blockIdx->XCD (%8), XCD x serves
// only quarter x%4; per-XCD gather working set = 1.6MB slice (L2-resident).
// Each quarter writes a partial head dot to partial[q*n+v]; k_sum4 combines.
//   k_hist -> k_scanA -> k_scanB -> k_binA2 -> k_fill2   (CSR, 0 glob atomics)
//   k_g1b  : 8 nodes/wave gather(xs16) + W1 + relu + W2 -> g16
//   k_g2q  : quarter-split gather(g16 slice) + combine + relu + Wf -> partial
//   k_sum4 : out = partial[0..3] + bf
// ---------------------------------------------------------------------------

#define NBLK 256
#define SHIFT 8          // 256 nodes/bucket; n <= 131072 -> <= 512 buckets
#define BMASK 255
#define NBUCK 512        // padded bucket count

// per-block bucket histogram -> part_T[bucket*NBLK + blk]  (no global atomics)
__global__ void k_hist(const int* __restrict__ dst, int* __restrict__ part, int E) {
    __shared__ int hist[NBUCK];
    int t = threadIdx.x;           // 256
    hist[t] = 0; hist[t + 256] = 0;
    __syncthreads();
    int E4 = E >> 2;
    int chunk4 = (E4 + NBLK - 1) / NBLK;
    int b = blockIdx.x;
    int s4 = b * chunk4;
    int e4 = min(s4 + chunk4, E4);
    const int4* dst4 = (const int4*)dst;
    for (int i = s4 + t; i < e4; i += 256) {
        int4 d = dst4[i];
        atomicAdd(&hist[d.x >> SHIFT], 1);
        atomicAdd(&hist[d.y >> SHIFT], 1);
        atomicAdd(&hist[d.z >> SHIFT], 1);
        atomicAdd(&hist[d.w >> SHIFT], 1);
    }
    if (b == NBLK - 1) {
        for (int e = (E4 << 2) + t; e < E; e += 256)
            atomicAdd(&hist[dst[e] >> SHIFT], 1);
    }
    __syncthreads();
    part[(size_t)t * NBLK + b] = hist[t];
    part[(size_t)(t + 256) * NBLK + b] = hist[t + 256];
}

// one wave per bucket: exclusive scan of its 256 partials; bucket total -> btot
__global__ void k_scanA(int* __restrict__ part, int* __restrict__ btot) {
    int t = threadIdx.x;           // 256 = 4 waves
    int b = blockIdx.x * 4 + (t >> 6);
    int lane = t & 63;
    int4* p4 = (int4*)(part + (size_t)b * NBLK);
    int4 v = p4[lane];
    int ls = v.x + v.y + v.z + v.w;
    int s = ls;
#pragma unroll
    for (int off = 1; off < 64; off <<= 1) {
        int u = __shfl_up(s, off, 64);
        if (lane >= off) s += u;
    }
    int base = s - ls;             // exclusive
    int4 o;
    o.x = base;
    o.y = base + v.x;
    o.z = o.y + v.y;
    o.w = o.z + v.z;
    p4[lane] = o;
    if (lane == 63) btot[b] = s;
}

// single block, 512 thr: exclusive scan of bucket totals -> bbase
__global__ void k_scanB(const int* __restrict__ btot, int* __restrict__ bbase,
                        int* __restrict__ rowptr, int n, int E) {
    __shared__ int tmp[NBUCK];
    int t = threadIdx.x;
    int v = btot[t];
    tmp[t] = v;
    __syncthreads();
    for (int off = 1; off < NBUCK; off <<= 1) {
        int add = (t >= off) ? tmp[t - off] : 0;
        __syncthreads();
        tmp[t] += add;
        __syncthreads();
    }
    bbase[t] = tmp[t] - v;
    if (t == NBUCK - 1) bbase[NBUCK] = tmp[NBUCK - 1];
    if (t == 0) rowptr[n] = E;
}

// bin edges into bucket-ordered packed words via block-private LDS cursors
__global__ void k_binA2(const int* __restrict__ src, const int* __restrict__ dst,
                        const int* __restrict__ part, const int* __restrict__ bbase,
                        int* __restrict__ bpair, int E) {
    __shared__ int cur[NBUCK];
    int t = threadIdx.x;           // 512
    int b = blockIdx.x;
    cur[t] = part[(size_t)t * NBLK + b] + bbase[t];
    __syncthreads();
    int E4 = E >> 2;
    int chunk4 = (E4 + NBLK - 1) / NBLK;
    int s4 = b * chunk4;
    int e4 = min(s4 + chunk4, E4);
    const int4* src4 = (const int4*)src;
    const int4* dst4 = (const int4*)dst;
    for (int i = s4 + t; i < e4; i += 512) {
        int4 s = src4[i];
        int4 d = dst4[i];
        int p0 = atomicAdd(&cur[d.x >> SHIFT], 1);
        bpair[p0] = (s.x << SHIFT) | (d.x & BMASK);
        int p1 = atomicAdd(&cur[d.y >> SHIFT], 1);
        bpair[p1] = (s.y << SHIFT) | (d.y & BMASK);
        int p2 = atomicAdd(&cur[d.z >> SHIFT], 1);
        bpair[p2] = (s.z << SHIFT) | (d.z & BMASK);
        int p3 = atomicAdd(&cur[d.w >> SHIFT], 1);
        bpair[p3] = (s.w << SHIFT) | (d.w & BMASK);
    }
    if (b == NBLK - 1) {
        for (int e = (E4 << 2) + t; e < E; e += 512) {
            int sv = src[e], dv = dst[e];
            int p = atomicAdd(&cur[dv >> SHIFT], 1);
            bpair[p] = (sv << SHIFT) | (dv & BMASK);
        }
    }
}

// one block (512 thr) per bucket: LDS counting sort -> rowptr/dis/col;
// fused xs16 = fp16(x * dis), 4 uints (8 halfs) per node
__global__ void k_fill2(const int* __restrict__ bpair, const int* __restrict__ bbase,
                        const float* __restrict__ x,
                        int* __restrict__ rowptr, float* __restrict__ dis,
                        unsigned int* __restrict__ xs16, int* __restrict__ col, int n) {
    __shared__ int cnt[256];
    __shared__ int tmp[256];
    __shared__ int cur[256];
    __shared__ float sdis[256];
    int b = blockIdx.x;
    int t = threadIdx.x;           // 512
    int start = bbase[b], end = bbase[b + 1];
    if (t < 256) cnt[t] = 0;
    __syncthreads();
    for (int i = start + t; i < end; i += 512)
        atomicAdd(&cnt[bpair[i] & BMASK], 1);
    __syncthreads();
    int v0 = (t < 256) ? cnt[t] : 0;
    if (t < 256) tmp[t] = v0;
    __syncthreads();
    for (int off = 1; off < 256; off <<= 1) {
        int add = (t < 256 && t >= off) ? tmp[t - off] : 0;
        __syncthreads();
        if (t < 256) tmp[t] += add;
        __syncthreads();
    }
    if (t < 256) {
        int v = (b << SHIFT) + t;
        if (v < n) {
            int r = start + tmp[t] - v0;
            rowptr[v] = r;
            cur[t] = r;
            float dv = rsqrtf(1.0f + (float)v0);
            dis[v] = dv;
            sdis[t] = dv;
        }
    }
    __syncthreads();
    int ubase = (b << SHIFT) * 4;
    int nu = n * 4;
    const float2* x2 = (const float2*)x;
    for (int i = t; i < 1024; i += 512) {
        int gi = ubase + i;
        if (gi < nu) {
            float d = sdis[i >> 2];
            float2 xv = x2[gi];
            __half2 h2 = __float22half2_rn(make_float2(xv.x * d, xv.y * d));
            xs16[gi] = *(unsigned int*)&h2;
        }
    }
    for (int i = start + t; i < end; i += 512) {
        int p = bpair[i];
        int pos = atomicAdd(&cur[p & BMASK], 1);
        col[pos] = p >> SHIFT;
    }
}

// layer 1, 8 nodes/wave: lane group of 8 per node; each lane gathers whole
// 16B xs16 rows; butterfly -> full agg8 in every lane; lane computes 4
// features of W1 and of W2 (h batched into regs via ds_read_b128).
__global__ void k_g1b(const int* __restrict__ rowptr, const int* __restrict__ col,
                      const uint4* __restrict__ xs16u4, const float* __restrict__ dis,
                      const float* __restrict__ W1, const float* __restrict__ b1,
                      const float* __restrict__ W2, uint2* __restrict__ g16u2, int n) {
    __shared__ float sW1[256];
    __shared__ float sW2[1024];
    __shared__ float sh[4][8][36];   // wave, node, feature (pad 36)
    int t = threadIdx.x;             // 256 = 4 waves
    sW1[t] = W1[t];
    for (int i = t; i < 1024; i += 256) sW2[i] = W2[i];
    __syncthreads();
    int widx = t >> 6, lane = t & 63;
    int nd = lane >> 3, j = lane & 7;
    int v = (blockIdx.x * 4 + widx) * 8 + nd;
    float a0 = 0.f, a1 = 0.f, a2 = 0.f, a3 = 0.f,
          a4 = 0.f, a5 = 0.f, a6 = 0.f, a7 = 0.f;
    int r0 = 0, r1 = 0;
    if (v < n) { r0 = rowptr[v]; r1 = rowptr[v + 1]; }
    for (int i = r0 + j; i < r1; i += 8) {
        uint4 raw = xs16u4[col[i]];
        float2 f0 = __half22float2(*(const __half2*)&raw.x);
        float2 f1 = __half22float2(*(const __half2*)&raw.y);
        float2 f2 = __half22float2(*(const __half2*)&raw.z);
        float2 f3 = __half22float2(*(const __half2*)&raw.w);
        a0 += f0.x; a1 += f0.y; a2 += f1.x; a3 += f1.y;
        a4 += f2.x; a5 += f2.y; a6 += f3.x; a7 += f3.y;
    }
    if (j == 0 && v < n) {           // self-loop
        uint4 raw = xs16u4[v];
        float2 f0 = __half22float2(*(const __half2*)&raw.x);
        float2 f1 = __half22float2(*(const __half2*)&raw.y);
        float2 f2 = __half22float2(*(const __half2*)&raw.z);
        float2 f3 = __half22float2(*(const __half2*)&raw.w);
        a0 += f0.x; a1 += f0.y; a2 += f1.x; a3 += f1.y;
        a4 += f2.x; a5 += f2.y; a6 += f3.x; a7 += f3.y;
    }
#pragma unroll
    for (int m = 1; m < 8; m <<= 1) {
        a0 += __shfl_xor(a0, m, 64);
        a1 += __shfl_xor(a1, m, 64);
        a2 += __shfl_xor(a2, m, 64);
        a3 += __shfl_xor(a3, m, 64);
        a4 += __shfl_xor(a4, m, 64);
        a5 += __shfl_xor(a5, m, 64);
        a6 += __shfl_xor(a6, m, 64);
        a7 += __shfl_xor(a7, m, 64);
    }
    float dv = (v < n) ? dis[v] : 0.f;
    int f0i = j * 4;
    float h0 = 0.f, h1 = 0.f, h2 = 0.f, h3 = 0.f;
    {
        float ak[8] = {a0, a1, a2, a3, a4, a5, a6, a7};
#pragma unroll
        for (int k = 0; k < 8; ++k) {
            float4 w = *(const float4*)&sW1[k * 32 + f0i];
            h0 += ak[k] * w.x; h1 += ak[k] * w.y;
            h2 += ak[k] * w.z; h3 += ak[k] * w.w;
        }
    }
    h0 = fmaxf(dv * h0 + b1[f0i + 0], 0.f);
    h1 = fmaxf(dv * h1 + b1[f0i + 1], 0.f);
    h2 = fmaxf(dv * h2 + b1[f0i + 2], 0.f);
    h3 = fmaxf(dv * h3 + b1[f0i + 3], 0.f);
    *(float4*)&sh[widx][nd][f0i] = make_float4(h0, h1, h2, h3);
    // same-wave LDS RAW: DS ops are in-order per wave
    const float4* hrow = (const float4*)&sh[widx][nd][0];
    float4 hr[8];
#pragma unroll
    for (int k4 = 0; k4 < 8; ++k4) hr[k4] = hrow[k4];
    float g0 = 0.f, g1 = 0.f, g2 = 0.f, g3 = 0.f;
#pragma unroll
    for (int k4 = 0; k4 < 8; ++k4) {
        float hk[4] = {hr[k4].x, hr[k4].y, hr[k4].z, hr[k4].w};
#pragma unroll
        for (int m = 0; m < 4; ++m) {
            float4 w = *(const float4*)&sW2[(k4 * 4 + m) * 32 + f0i];
            g0 += hk[m] * w.x; g1 += hk[m] * w.y;
            g2 += hk[m] * w.z; g3 += hk[m] * w.w;
        }
    }
    if (v < n) {
        __half2 ha = __float22half2_rn(make_float2(g0 * dv, g1 * dv));
        __half2 hb = __float22half2_rn(make_float2(g2 * dv, g3 * dv));
        uint2 o;
        o.x = *(unsigned int*)&ha;
        o.y = *(unsigned int*)&hb;
        g16u2[(size_t)v * 8 + j] = o;
    }
}

// layer 2 + head, quarter-split: quarter = blockIdx%4 (XCD-clustered),
// 2 lanes/node x 32 nodes/wave, each lane gathers the node's 16B quarter
// slice; pair-reduce; lane 0 computes the quarter's partial head dot.
__global__ void k_g2q(const int* __restrict__ rowptr, const int* __restrict__ col,
                      const uint4* __restrict__ g16u4, const float* __restrict__ dis,
                      const float* __restrict__ b2, const float* __restrict__ Wf,
                      float* __restrict__ partial, int n) {
    int q = blockIdx.x & 3;
    int chunk = blockIdx.x >> 2;
    int t = threadIdx.x;             // 256 = 4 waves x 32 nodes
    int wave = t >> 6, lane = t & 63;
    int nd = lane >> 1, sub = lane & 1;
    int v = chunk * 128 + wave * 32 + nd;
    if (v >= n) return;
    int r0 = rowptr[v], r1 = rowptr[v + 1];
    float4 s0 = make_float4(0.f, 0.f, 0.f, 0.f);
    float4 s1 = make_float4(0.f, 0.f, 0.f, 0.f);
    if (sub == 0) {                  // self-loop
        uint4 raw = g16u4[(size_t)v * 4 + q];
        float2 f0 = __half22float2(*(const __half2*)&raw.x);
        float2 f1 = __half22float2(*(const __half2*)&raw.y);
        float2 f2 = __half22float2(*(const __half2*)&raw.z);
        float2 f3 = __half22float2(*(const __half2*)&raw.w);
        s0.x += f0.x; s0.y += f0.y; s0.z += f1.x; s0.w += f1.y;
        s1.x += f2.x; s1.y += f2.y; s1.z += f3.x; s1.w += f3.y;
    }
    for (int i = r0 + sub; i < r1; i += 2) {
        uint4 raw = g16u4[(size_t)col[i] * 4 + q];
        float2 f0 = __half22float2(*(const __half2*)&raw.x);
        float2 f1 = __half22float2(*(const __half2*)&raw.y);
        float2 f2 = __half22float2(*(const __half2*)&raw.z);
        float2 f3 = __half22float2(*(const __half2*)&raw.w);
        s0.x += f0.x; s0.y += f0.y; s0.z += f1.x; s0.w += f1.y;
        s1.x += f2.x; s1.y += f2.y; s1.z += f3.x; s1.w += f3.y;
    }
    // pair reduce (lanes sub and sub^1)
    s0.x += __shfl_xor(s0.x, 1, 64);
    s0.y += __shfl_xor(s0.y, 1, 64);
    s0.z += __shfl_xor(s0.z, 1, 64);
    s0.w += __shfl_xor(s0.w, 1, 64);
    s1.x += __shfl_xor(s1.x, 1, 64);
    s1.y += __shfl_xor(s1.y, 1, 64);
    s1.z += __shfl_xor(s1.z, 1, 64);
    s1.w += __shfl_xor(s1.w, 1, 64);
    if (sub == 0) {
        float dv = dis[v];
        float4 bv0 = ((const float4*)b2)[q * 2], bv1 = ((const float4*)b2)[q * 2 + 1];
        float4 wv0 = ((const float4*)Wf)[q * 2], wv1 = ((const float4*)Wf)[q * 2 + 1];
        float p = fmaxf(dv * s0.x + bv0.x, 0.f) * wv0.x
                + fmaxf(dv * s0.y + bv0.y, 0.f) * wv0.y
                + fmaxf(dv * s0.z + bv0.z, 0.f) * wv0.z
                + fmaxf(dv * s0.w + bv0.w, 0.f) * wv0.w
                + fmaxf(dv * s1.x + bv1.x, 0.f) * wv1.x
                + fmaxf(dv * s1.y + bv1.y, 0.f) * wv1.y
                + fmaxf(dv * s1.z + bv1.z, 0.f) * wv1.z
                + fmaxf(dv * s1.w + bv1.w, 0.f) * wv1.w;
        partial[(size_t)q * n + v] = p;
    }
}

// out[v] = partial[0][v] + partial[1][v] + partial[2][v] + partial[3][v] + bf
__global__ void k_sum4(const float* __restrict__ partial, const float* __restrict__ bf,
                       float* __restrict__ out, int n) {
    int v = blockIdx.x * 256 + threadIdx.x;
    if (v >= n) return;
    out[v] = partial[v] + partial[(size_t)n + v] + partial[(size_t)2 * n + v]
           + partial[(size_t)3 * n + v] + bf[0];
}

extern "C" void kernel_launch(void* const* d_in, const int* in_sizes, int n_in,
                              void* d_out, int out_size, void* d_ws, size_t ws_size,
                              hipStream_t stream) {
    const float* x  = (const float*)d_in[0];
    const int*   ei = (const int*)d_in[1];   // [2, E] int32
    const float* W1 = (const float*)d_in[2];
    const float* b1 = (const float*)d_in[3];
    const float* W2 = (const float*)d_in[4];
    const float* b2 = (const float*)d_in[5];
    const float* Wf = (const float*)d_in[6];
    const float* bf = (const float*)d_in[7];
    float* out = (float*)d_out;

    const int n = in_sizes[0] / 8;
    const int E = in_sizes[1] / 2;
    const int* src = ei;
    const int* dst = ei + E;
    const int nbuck = (n + 255) >> 8;        // active buckets
    const size_t na = (size_t)((n + 3) & ~3);  // align fp16 arrays to 16B

    // workspace (~27 MB)
    float* dis         = (float*)d_ws;                  // n
    unsigned int* xs16 = (unsigned int*)(dis + na);     // 4n uints (8 halfs/node)
    unsigned int* g16  = xs16 + na * 4;                 // 16n uints (32 halfs/node)
    float* partial     = (float*)(g16 + na * 16);       // 4n
    int* rowptr        = (int*)(partial + na * 4);      // n+1
    int* bbase         = rowptr + (n + 1);              // NBUCK+1
    int* btot          = bbase + (NBUCK + 1);           // NBUCK
    int* part          = btot + NBUCK + 2;              // NBUCK*NBLK (align 16B)
    int* col           = part + (size_t)NBUCK * NBLK;   // E
    int* bpair         = col + E;                       // E

    // --- CSR build (zero global atomics, fully parallel scan) ---
    k_hist <<<dim3(NBLK),      dim3(256), 0, stream>>>(dst, part, E);
    k_scanA<<<dim3(NBUCK / 4), dim3(256), 0, stream>>>(part, btot);
    k_scanB<<<dim3(1),         dim3(NBUCK), 0, stream>>>(btot, bbase, rowptr, n, E);
    k_binA2<<<dim3(NBLK),      dim3(512), 0, stream>>>(src, dst, part, bbase, bpair, E);
    k_fill2<<<dim3(nbuck),     dim3(512), 0, stream>>>(bpair, bbase, x, rowptr, dis, xs16, col, n);

    // --- layer 1 (8 nodes/wave, gather + W1 + relu + W2) -> g16 ---
    k_g1b<<<dim3((n + 31) / 32), dim3(256), 0, stream>>>(rowptr, col, (const uint4*)xs16,
                                                         dis, W1, b1, W2, (uint2*)g16, n);

    // --- layer 2 + head, quarter-split (XCD-clustered) ---
    const int nchunk = (n + 127) / 128;
    k_g2q<<<dim3(4 * nchunk), dim3(256), 0, stream>>>(rowptr, col, (const uint4*)g16, dis,
                                                      b2, Wf, partial, n);
    k_sum4<<<dim3((n + 255) / 256), dim3(256), 0, stream>>>(partial, bf, out, n);
}

// Round 14
// 91.408 us; speedup vs baseline: 2.0941x; 2.0941x over previous
//
#include <hip/hip_runtime.h>
#include <hip/hip_fp16.h>

// ---------------------------------------------------------------------------
// RoutingGNN: 2-layer GCN (sym-norm, self-loops) + linear head.
// Round 14: revert round-13's quarter-split (16B-slice gathers still fetch
// full 64B lines -> 6x FETCH, 123us). Back to round-12 structure (95us).
// One tweak: k_g2f gather loop manually 2-way unrolled with dual accumulator
// sets (2 col reads + 2 row gathers in flight per lane).
//   k_hist -> k_scanA -> k_scanB -> k_binA2 -> k_fill2   (CSR, 0 glob atomics)
//   k_g1b  : 8 nodes/wave gather(xs16) + W1 + relu + W2 -> g16
//   k_g2f  : 8 nodes/wave gather(g16) + combine + relu + Wf head -> out
// ---------------------------------------------------------------------------

#define NBLK 256
#define SHIFT 8          // 256 nodes/bucket; n <= 131072 -> <= 512 buckets
#define BMASK 255
#define NBUCK 512        // padded bucket count

// per-block bucket histogram -> part_T[bucket*NBLK + blk]  (no global atomics)
__global__ void k_hist(const int* __restrict__ dst, int* __restrict__ part, int E) {
    __shared__ int hist[NBUCK];
    int t = threadIdx.x;           // 256
    hist[t] = 0; hist[t + 256] = 0;
    __syncthreads();
    int E4 = E >> 2;
    int chunk4 = (E4 + NBLK - 1) / NBLK;
    int b = blockIdx.x;
    int s4 = b * chunk4;
    int e4 = min(s4 + chunk4, E4);
    const int4* dst4 = (const int4*)dst;
    for (int i = s4 + t; i < e4; i += 256) {
        int4 d = dst4[i];
        atomicAdd(&hist[d.x >> SHIFT], 1);
        atomicAdd(&hist[d.y >> SHIFT], 1);
        atomicAdd(&hist[d.z >> SHIFT], 1);
        atomicAdd(&hist[d.w >> SHIFT], 1);
    }
    if (b == NBLK - 1) {
        for (int e = (E4 << 2) + t; e < E; e += 256)
            atomicAdd(&hist[dst[e] >> SHIFT], 1);
    }
    __syncthreads();
    part[(size_t)t * NBLK + b] = hist[t];
    part[(size_t)(t + 256) * NBLK + b] = hist[t + 256];
}

// one wave per bucket: exclusive scan of its 256 partials; bucket total -> btot
__global__ void k_scanA(int* __restrict__ part, int* __restrict__ btot) {
    int t = threadIdx.x;           // 256 = 4 waves
    int b = blockIdx.x * 4 + (t >> 6);
    int lane = t & 63;
    int4* p4 = (int4*)(part + (size_t)b * NBLK);
    int4 v = p4[lane];
    int ls = v.x + v.y + v.z + v.w;
    int s = ls;
#pragma unroll
    for (int off = 1; off < 64; off <<= 1) {
        int u = __shfl_up(s, off, 64);
        if (lane >= off) s += u;
    }
    int base = s - ls;             // exclusive
    int4 o;
    o.x = base;
    o.y = base + v.x;
    o.z = o.y + v.y;
    o.w = o.z + v.z;
    p4[lane] = o;
    if (lane == 63) btot[b] = s;
}

// single block, 512 thr: exclusive scan of bucket totals -> bbase
__global__ void k_scanB(const int* __restrict__ btot, int* __restrict__ bbase,
                        int* __restrict__ rowptr, int n, int E) {
    __shared__ int tmp[NBUCK];
    int t = threadIdx.x;
    int v = btot[t];
    tmp[t] = v;
    __syncthreads();
    for (int off = 1; off < NBUCK; off <<= 1) {
        int add = (t >= off) ? tmp[t - off] : 0;
        __syncthreads();
        tmp[t] += add;
        __syncthreads();
    }
    bbase[t] = tmp[t] - v;
    if (t == NBUCK - 1) bbase[NBUCK] = tmp[NBUCK - 1];
    if (t == 0) rowptr[n] = E;
}

// bin edges into bucket-ordered packed words via block-private LDS cursors
__global__ void k_binA2(const int* __restrict__ src, const int* __restrict__ dst,
                        const int* __restrict__ part, const int* __restrict__ bbase,
                        int* __restrict__ bpair, int E) {
    __shared__ int cur[NBUCK];
    int t = threadIdx.x;           // 512
    int b = blockIdx.x;
    cur[t] = part[(size_t)t * NBLK + b] + bbase[t];
    __syncthreads();
    int E4 = E >> 2;
    int chunk4 = (E4 + NBLK - 1) / NBLK;
    int s4 = b * chunk4;
    int e4 = min(s4 + chunk4, E4);
    const int4* src4 = (const int4*)src;
    const int4* dst4 = (const int4*)dst;
    for (int i = s4 + t; i < e4; i += 512) {
        int4 s = src4[i];
        int4 d = dst4[i];
        int p0 = atomicAdd(&cur[d.x >> SHIFT], 1);
        bpair[p0] = (s.x << SHIFT) | (d.x & BMASK);
        int p1 = atomicAdd(&cur[d.y >> SHIFT], 1);
        bpair[p1] = (s.y << SHIFT) | (d.y & BMASK);
        int p2 = atomicAdd(&cur[d.z >> SHIFT], 1);
        bpair[p2] = (s.z << SHIFT) | (d.z & BMASK);
        int p3 = atomicAdd(&cur[d.w >> SHIFT], 1);
        bpair[p3] = (s.w << SHIFT) | (d.w & BMASK);
    }
    if (b == NBLK - 1) {
        for (int e = (E4 << 2) + t; e < E; e += 512) {
            int sv = src[e], dv = dst[e];
            int p = atomicAdd(&cur[dv >> SHIFT], 1);
            bpair[p] = (sv << SHIFT) | (dv & BMASK);
        }
    }
}

// one block (512 thr) per bucket: LDS counting sort -> rowptr/dis/col;
// fused xs16 = fp16(x * dis), 4 uints (8 halfs) per node
__global__ void k_fill2(const int* __restrict__ bpair, const int* __restrict__ bbase,
                        const float* __restrict__ x,
                        int* __restrict__ rowptr, float* __restrict__ dis,
                        unsigned int* __restrict__ xs16, int* __restrict__ col, int n) {
    __shared__ int cnt[256];
    __shared__ int tmp[256];
    __shared__ int cur[256];
    __shared__ float sdis[256];
    int b = blockIdx.x;
    int t = threadIdx.x;           // 512
    int start = bbase[b], end = bbase[b + 1];
    if (t < 256) cnt[t] = 0;
    __syncthreads();
    for (int i = start + t; i < end; i += 512)
        atomicAdd(&cnt[bpair[i] & BMASK], 1);
    __syncthreads();
    int v0 = (t < 256) ? cnt[t] : 0;
    if (t < 256) tmp[t] = v0;
    __syncthreads();
    for (int off = 1; off < 256; off <<= 1) {
        int add = (t < 256 && t >= off) ? tmp[t - off] : 0;
        __syncthreads();
        if (t < 256) tmp[t] += add;
        __syncthreads();
    }
    if (t < 256) {
        int v = (b << SHIFT) + t;
        if (v < n) {
            int r = start + tmp[t] - v0;
            rowptr[v] = r;
            cur[t] = r;
            float dv = rsqrtf(1.0f + (float)v0);
            dis[v] = dv;
            sdis[t] = dv;
        }
    }
    __syncthreads();
    int ubase = (b << SHIFT) * 4;
    int nu = n * 4;
    const float2* x2 = (const float2*)x;
    for (int i = t; i < 1024; i += 512) {
        int gi = ubase + i;
        if (gi < nu) {
            float d = sdis[i >> 2];
            float2 xv = x2[gi];
            __half2 h2 = __float22half2_rn(make_float2(xv.x * d, xv.y * d));
            xs16[gi] = *(unsigned int*)&h2;
        }
    }
    for (int i = start + t; i < end; i += 512) {
        int p = bpair[i];
        int pos = atomicAdd(&cur[p & BMASK], 1);
        col[pos] = p >> SHIFT;
    }
}

// layer 1, 8 nodes/wave: lane group of 8 per node; each lane gathers whole
// 16B xs16 rows; butterfly -> full agg8 in every lane; lane computes 4
// features of W1 and of W2 (h batched into regs via ds_read_b128).
__global__ void k_g1b(const int* __restrict__ rowptr, const int* __restrict__ col,
                      const uint4* __restrict__ xs16u4, const float* __restrict__ dis,
                      const float* __restrict__ W1, const float* __restrict__ b1,
                      const float* __restrict__ W2, uint2* __restrict__ g16u2, int n) {
    __shared__ float sW1[256];
    __shared__ float sW2[1024];
    __shared__ float sh[4][8][36];   // wave, node, feature (pad 36)
    int t = threadIdx.x;             // 256 = 4 waves
    sW1[t] = W1[t];
    for (int i = t; i < 1024; i += 256) sW2[i] = W2[i];
    __syncthreads();
    int widx = t >> 6, lane = t & 63;
    int nd = lane >> 3, j = lane & 7;
    int v = (blockIdx.x * 4 + widx) * 8 + nd;
    float a0 = 0.f, a1 = 0.f, a2 = 0.f, a3 = 0.f,
          a4 = 0.f, a5 = 0.f, a6 = 0.f, a7 = 0.f;
    int r0 = 0, r1 = 0;
    if (v < n) { r0 = rowptr[v]; r1 = rowptr[v + 1]; }
    for (int i = r0 + j; i < r1; i += 8) {
        uint4 raw = xs16u4[col[i]];
        float2 f0 = __half22float2(*(const __half2*)&raw.x);
        float2 f1 = __half22float2(*(const __half2*)&raw.y);
        float2 f2 = __half22float2(*(const __half2*)&raw.z);
        float2 f3 = __half22float2(*(const __half2*)&raw.w);
        a0 += f0.x; a1 += f0.y; a2 += f1.x; a3 += f1.y;
        a4 += f2.x; a5 += f2.y; a6 += f3.x; a7 += f3.y;
    }
    if (j == 0 && v < n) {           // self-loop
        uint4 raw = xs16u4[v];
        float2 f0 = __half22float2(*(const __half2*)&raw.x);
        float2 f1 = __half22float2(*(const __half2*)&raw.y);
        float2 f2 = __half22float2(*(const __half2*)&raw.z);
        float2 f3 = __half22float2(*(const __half2*)&raw.w);
        a0 += f0.x; a1 += f0.y; a2 += f1.x; a3 += f1.y;
        a4 += f2.x; a5 += f2.y; a6 += f3.x; a7 += f3.y;
    }
#pragma unroll
    for (int m = 1; m < 8; m <<= 1) {
        a0 += __shfl_xor(a0, m, 64);
        a1 += __shfl_xor(a1, m, 64);
        a2 += __shfl_xor(a2, m, 64);
        a3 += __shfl_xor(a3, m, 64);
        a4 += __shfl_xor(a4, m, 64);
        a5 += __shfl_xor(a5, m, 64);
        a6 += __shfl_xor(a6, m, 64);
        a7 += __shfl_xor(a7, m, 64);
    }
    float dv = (v < n) ? dis[v] : 0.f;
    int f0i = j * 4;
    float h0 = 0.f, h1 = 0.f, h2 = 0.f, h3 = 0.f;
    {
        float ak[8] = {a0, a1, a2, a3, a4, a5, a6, a7};
#pragma unroll
        for (int k = 0; k < 8; ++k) {
            float4 w = *(const float4*)&sW1[k * 32 + f0i];
            h0 += ak[k] * w.x; h1 += ak[k] * w.y;
            h2 += ak[k] * w.z; h3 += ak[k] * w.w;
        }
    }
    h0 = fmaxf(dv * h0 + b1[f0i + 0], 0.f);
    h1 = fmaxf(dv * h1 + b1[f0i + 1], 0.f);
    h2 = fmaxf(dv * h2 + b1[f0i + 2], 0.f);
    h3 = fmaxf(dv * h3 + b1[f0i + 3], 0.f);
    *(float4*)&sh[widx][nd][f0i] = make_float4(h0, h1, h2, h3);
    // same-wave LDS RAW: DS ops are in-order per wave
    const float4* hrow = (const float4*)&sh[widx][nd][0];
    float4 hr[8];
#pragma unroll
    for (int k4 = 0; k4 < 8; ++k4) hr[k4] = hrow[k4];
    float g0 = 0.f, g1 = 0.f, g2 = 0.f, g3 = 0.f;
#pragma unroll
    for (int k4 = 0; k4 < 8; ++k4) {
        float hk[4] = {hr[k4].x, hr[k4].y, hr[k4].z, hr[k4].w};
#pragma unroll
        for (int m = 0; m < 4; ++m) {
            float4 w = *(const float4*)&sW2[(k4 * 4 + m) * 32 + f0i];
            g0 += hk[m] * w.x; g1 += hk[m] * w.y;
            g2 += hk[m] * w.z; g3 += hk[m] * w.w;
        }
    }
    if (v < n) {
        __half2 ha = __float22half2_rn(make_float2(g0 * dv, g1 * dv));
        __half2 hb = __float22half2_rn(make_float2(g2 * dv, g3 * dv));
        uint2 o;
        o.x = *(unsigned int*)&ha;
        o.y = *(unsigned int*)&hb;
        g16u2[(size_t)v * 8 + j] = o;
    }
}

// layer 2 + head: 8 lanes/node (2 edge-slots x 4 quarters), 8 nodes/wave.
// Gather loop 2-way unrolled with dual accumulator sets for deeper MLP.
__global__ void k_g2f(const int* __restrict__ rowptr, const int* __restrict__ col,
                      const uint4* __restrict__ g16u4, const float* __restrict__ dis,
                      const float* __restrict__ b2, const float* __restrict__ Wf,
                      const float* __restrict__ bf, float* __restrict__ out, int n) {
    int t = threadIdx.x;
    int wave = t >> 6, lane = t & 63;
    int nd = lane >> 3, sub = lane & 7;
    int slot = sub >> 2, q = sub & 3;
    int v = (blockIdx.x * 4 + wave) * 8 + nd;
    if (v >= n) return;              // whole 8-lane group exits together
    int r0 = rowptr[v], r1 = rowptr[v + 1];
    float4 s0 = make_float4(0.f, 0.f, 0.f, 0.f);
    float4 s1 = make_float4(0.f, 0.f, 0.f, 0.f);
    float4 t0 = make_float4(0.f, 0.f, 0.f, 0.f);
    float4 t1 = make_float4(0.f, 0.f, 0.f, 0.f);
    if (slot == 0) {                 // self-loop
        uint4 raw = g16u4[(size_t)v * 4 + q];
        float2 f0 = __half22float2(*(const __half2*)&raw.x);
        float2 f1 = __half22float2(*(const __half2*)&raw.y);
        float2 f2 = __half22float2(*(const __half2*)&raw.z);
        float2 f3 = __half22float2(*(const __half2*)&raw.w);
        s0.x += f0.x; s0.y += f0.y; s0.z += f1.x; s0.w += f1.y;
        s1.x += f2.x; s1.y += f2.y; s1.z += f3.x; s1.w += f3.y;
    }
    int i = r0 + slot;
    for (; i + 2 < r1; i += 4) {     // two trips per iteration
        int cA = col[i], cB = col[i + 2];
        uint4 rawA = g16u4[(size_t)cA * 4 + q];
        uint4 rawB = g16u4[(size_t)cB * 4 + q];
        float2 a0 = __half22float2(*(const __half2*)&rawA.x);
        float2 a1 = __half22float2(*(const __half2*)&rawA.y);
        float2 a2 = __half22float2(*(const __half2*)&rawA.z);
        float2 a3 = __half22float2(*(const __half2*)&rawA.w);
        s0.x += a0.x; s0.y += a0.y; s0.z += a1.x; s0.w += a1.y;
        s1.x += a2.x; s1.y += a2.y; s1.z += a3.x; s1.w += a3.y;
        float2 b0 = __half22float2(*(const __half2*)&rawB.x);
        float2 b1v = __half22float2(*(const __half2*)&rawB.y);
        float2 b2v = __half22float2(*(const __half2*)&rawB.z);
        float2 b3 = __half22float2(*(const __half2*)&rawB.w);
        t0.x += b0.x; t0.y += b0.y; t0.z += b1v.x; t0.w += b1v.y;
        t1.x += b2v.x; t1.y += b2v.y; t1.z += b3.x; t1.w += b3.y;
    }
    if (i < r1) {
        uint4 raw = g16u4[(size_t)col[i] * 4 + q];
        float2 f0 = __half22float2(*(const __half2*)&raw.x);
        float2 f1 = __half22float2(*(const __half2*)&raw.y);
        float2 f2 = __half22float2(*(const __half2*)&raw.z);
        float2 f3 = __half22float2(*(const __half2*)&raw.w);
        s0.x += f0.x; s0.y += f0.y; s0.z += f1.x; s0.w += f1.y;
        s1.x += f2.x; s1.y += f2.y; s1.z += f3.x; s1.w += f3.y;
    }
    s0.x += t0.x; s0.y += t0.y; s0.z += t0.z; s0.w += t0.w;
    s1.x += t1.x; s1.y += t1.y; s1.z += t1.z; s1.w += t1.w;
    // slot reduce (lanes sub and sub^4)
    s0.x += __shfl_xor(s0.x, 4, 64);
    s0.y += __shfl_xor(s0.y, 4, 64);
    s0.z += __shfl_xor(s0.z, 4, 64);
    s0.w += __shfl_xor(s0.w, 4, 64);
    s1.x += __shfl_xor(s1.x, 4, 64);
    s1.y += __shfl_xor(s1.y, 4, 64);
    s1.z += __shfl_xor(s1.z, 4, 64);
    s1.w += __shfl_xor(s1.w, 4, 64);
    float dv = dis[v];
    float4 bv0 = ((const float4*)b2)[q * 2], bv1 = ((const float4*)b2)[q * 2 + 1];
    float4 wv0 = ((const float4*)Wf)[q * 2], wv1 = ((const float4*)Wf)[q * 2 + 1];
    float p = fmaxf(dv * s0.x + bv0.x, 0.f) * wv0.x
            + fmaxf(dv * s0.y + bv0.y, 0.f) * wv0.y
            + fmaxf(dv * s0.z + bv0.z, 0.f) * wv0.z
            + fmaxf(dv * s0.w + bv0.w, 0.f) * wv0.w
            + fmaxf(dv * s1.x + bv1.x, 0.f) * wv1.x
            + fmaxf(dv * s1.y + bv1.y, 0.f) * wv1.y
            + fmaxf(dv * s1.z + bv1.z, 0.f) * wv1.z
            + fmaxf(dv * s1.w + bv1.w, 0.f) * wv1.w;
    p += __shfl_xor(p, 1, 64);
    p += __shfl_xor(p, 2, 64);
    if (sub == 0) out[v] = p + bf[0];
}

extern "C" void kernel_launch(void* const* d_in, const int* in_sizes, int n_in,
                              void* d_out, int out_size, void* d_ws, size_t ws_size,
                              hipStream_t stream) {
    const float* x  = (const float*)d_in[0];
    const int*   ei = (const int*)d_in[1];   // [2, E] int32
    const float* W1 = (const float*)d_in[2];
    const float* b1 = (const float*)d_in[3];
    const float* W2 = (const float*)d_in[4];
    const float* b2 = (const float*)d_in[5];
    const float* Wf = (const float*)d_in[6];
    const float* bf = (const float*)d_in[7];
    float* out = (float*)d_out;

    const int n = in_sizes[0] / 8;
    const int E = in_sizes[1] / 2;
    const int* src = ei;
    const int* dst = ei + E;
    const int nbuck = (n + 255) >> 8;        // active buckets
    const size_t na = (size_t)((n + 3) & ~3);  // align fp16 arrays to 16B

    // workspace (~25 MB)
    float* dis         = (float*)d_ws;                  // n
    unsigned int* xs16 = (unsigned int*)(dis + na);     // 4n uints (8 halfs/node)
    unsigned int* g16  = xs16 + na * 4;                 // 16n uints (32 halfs/node)
    int* rowptr        = (int*)(g16 + na * 16);         // n+1
    int* bbase         = rowptr + (n + 1);              // NBUCK+1
    int* btot          = bbase + (NBUCK + 1);           // NBUCK
    int* part          = btot + NBUCK + 2;              // NBUCK*NBLK (align 16B)
    int* col           = part + (size_t)NBUCK * NBLK;   // E
    int* bpair         = col + E;                       // E

    // --- CSR build (zero global atomics, fully parallel scan) ---
    k_hist <<<dim3(NBLK),      dim3(256), 0, stream>>>(dst, part, E);
    k_scanA<<<dim3(NBUCK / 4), dim3(256), 0, stream>>>(part, btot);
    k_scanB<<<dim3(1),         dim3(NBUCK), 0, stream>>>(btot, bbase, rowptr, n, E);
    k_binA2<<<dim3(NBLK),      dim3(512), 0, stream>>>(src, dst, part, bbase, bpair, E);
    k_fill2<<<dim3(nbuck),     dim3(512), 0, stream>>>(bpair, bbase, x, rowptr, dis, xs16, col, n);

    // --- layer 1 (8 nodes/wave, gather + W1 + relu + W2) -> g16 ---
    k_g1b<<<dim3((n + 31) / 32), dim3(256), 0, stream>>>(rowptr, col, (const uint4*)xs16,
                                                         dis, W1, b1, W2, (uint2*)g16, n);

    // --- layer 2 + head (8 nodes/wave, 2 edge slots, 2x unrolled) ---
    k_g2f<<<dim3((n + 31) / 32), dim3(256), 0, stream>>>(rowptr, col, (const uint4*)g16, dis,
                                                         b2, Wf, bf, out, n);
}